// Round 1
// baseline (3262.332 us; speedup 1.0000x reference)
//
#include <hip/hip_runtime.h>

// ---------------------------------------------------------------------------
// SelectiveSSM (Mamba block) forward on MI355X / gfx950.
// Pipeline: cvt(fp32->fp16) -> GEMM1 (x@W_in^T, split xi/z) -> causal depthwise
// conv+SiLU -> GEMM2 (xi@W_xproj^T, split dt_lo/B/C) -> GEMM3 (dt_lo@W_dt^T +
// b_dt, softplus) -> sequential selective scan + gating -> GEMM4 (y@W_out^T).
// All GEMMs: fp16 MFMA 16x16x32, 128x128 tile, BK=32, m97-style K loop.
// ---------------------------------------------------------------------------

#define DM   1024
#define DI   2048
#define DSTATE 16
#define DTR  64
#define BSZ  4
#define LSEQ 4096
#define NTOK (BSZ * LSEQ)   // 16384

typedef _Float16 half8 __attribute__((ext_vector_type(8)));
typedef _Float16 half4v __attribute__((ext_vector_type(4)));
typedef float f32x4 __attribute__((ext_vector_type(4)));

__device__ __forceinline__ void load_lds16(const _Float16* g, _Float16* l) {
    __builtin_amdgcn_global_load_lds(
        (const __attribute__((address_space(1))) void*)g,
        (__attribute__((address_space(3))) void*)l,
        16, 0, 0);
}

// ------------------------------ conversions --------------------------------

__global__ __launch_bounds__(256) void cvt_f32_f16(const float* __restrict__ in,
                                                   _Float16* __restrict__ out,
                                                   long nvec) {
    long i = (long)blockIdx.x * 256 + threadIdx.x;
    if (i >= nvec) return;
    f32x4 v = ((const f32x4*)in)[i];
    half4v o;
    o[0] = (_Float16)v[0]; o[1] = (_Float16)v[1];
    o[2] = (_Float16)v[2]; o[3] = (_Float16)v[3];
    ((half4v*)out)[i] = o;
}

// W_xproj is (96, 2048); pad to (128, 2048) with zeros so the GEMM N-tile is full.
__global__ __launch_bounds__(256) void cvt_pad_wxp(const float* __restrict__ in,
                                                   _Float16* __restrict__ out) {
    int i = blockIdx.x * 256 + threadIdx.x;   // over 128*2048
    int row = i >> 11;
    int col = i & 2047;
    out[i] = (row < 96) ? (_Float16)in[row * 2048 + col] : (_Float16)0.f;
}

// ------------------------------ GEMM (NT) ----------------------------------
// C[m,n] = sum_k A[m,k] * B[n,k].  A: (M,K) fp16 row-major. B: (N,K) fp16
// row-major. 128x128 tile, BK=32, 256 threads (4 waves, 2x2 wave grid, each
// wave 64x64 = 4x4 MFMA 16x16x32 tiles). Epilogue via functor.

struct EpiSplit {          // GEMM1: n<2048 -> xi_raw(f16), else z(f16)
    _Float16* xi; _Float16* z;
    __device__ void store(int m, int n, float v) const {
        if (n < DI) xi[(long)m * DI + n] = (_Float16)v;
        else        z[(long)m * DI + (n - DI)] = (_Float16)v;
    }
};
struct EpiXproj {          // GEMM2: n<64 -> dt_lo(f16); 64..95 -> BC(f32)
    _Float16* dtlo; float* BC;
    __device__ void store(int m, int n, float v) const {
        if (n < DTR)      dtlo[(long)m * DTR + n] = (_Float16)v;
        else if (n < 96)  BC[(long)m * 32 + (n - DTR)] = v;
    }
};
struct EpiDt {             // GEMM3: softplus(v + b_dt[n]) -> dt(f16)
    const float* b_dt; _Float16* dt;
    __device__ void store(int m, int n, float v) const {
        float t = v + b_dt[n];
        float sp = (t > 20.f) ? t : log1pf(__expf(t));
        dt[(long)m * DI + n] = (_Float16)sp;
    }
};
struct EpiOut {            // GEMM4: plain fp32 store
    float* out;
    __device__ void store(int m, int n, float v) const {
        out[(long)m * DM + n] = v;
    }
};

template <class Epi>
__global__ __launch_bounds__(256, 2) void gemm_nt(const _Float16* __restrict__ A,
                                                  const _Float16* __restrict__ B,
                                                  int K, Epi epi) {
    __shared__ __align__(16) _Float16 As[128 * 32];
    __shared__ __align__(16) _Float16 Bs[128 * 32];
    const int tid  = threadIdx.x;
    const int wave = tid >> 6;
    const int ln   = tid & 63;
    const int wm   = wave & 1;      // 2x2 wave grid over the 128x128 tile
    const int wn   = wave >> 1;
    const int lane_m = ln & 15;     // MFMA A/B operand: row/col = lane&15
    const int kg     = ln >> 4;     // k-group: 8 halves each

    const long Abase = (long)blockIdx.y * 128 * K;
    const long Bbase = (long)blockIdx.x * 128 * K;

    f32x4 acc[4][4];
#pragma unroll
    for (int i = 0; i < 4; ++i)
#pragma unroll
        for (int j = 0; j < 4; ++j) acc[i][j] = (f32x4){0.f, 0.f, 0.f, 0.f};

    for (int k0 = 0; k0 < K; k0 += 32) {
        __syncthreads();   // protect LDS from previous iteration's readers
#pragma unroll
        for (int c = 0; c < 2; ++c) {
            int lin = tid + c * 256;           // 0..511
            int row = lin >> 2;                // 128 rows
            int col = (lin & 3) << 3;          // 4 chunks of 8 halves
            // LDS dest is wave-uniform base + lane*16B; our linear layout matches.
            load_lds16(A + Abase + (long)row * K + k0 + col,
                       As + (size_t)(wave * 64 + c * 256) * 8);
            load_lds16(B + Bbase + (long)row * K + k0 + col,
                       Bs + (size_t)(wave * 64 + c * 256) * 8);
        }
        asm volatile("s_waitcnt vmcnt(0)" ::: "memory");
        __syncthreads();

        half8 a[4], b[4];
#pragma unroll
        for (int i = 0; i < 4; ++i)
            a[i] = *(const half8*)&As[(wm * 64 + i * 16 + lane_m) * 32 + kg * 8];
#pragma unroll
        for (int j = 0; j < 4; ++j)
            b[j] = *(const half8*)&Bs[(wn * 64 + j * 16 + lane_m) * 32 + kg * 8];
#pragma unroll
        for (int i = 0; i < 4; ++i)
#pragma unroll
            for (int j = 0; j < 4; ++j)
                acc[i][j] = __builtin_amdgcn_mfma_f32_16x16x32_f16(a[i], b[j], acc[i][j], 0, 0, 0);
    }

    // C/D layout: row m = (lane>>4)*4 + reg, col n = lane&15  (verified m89)
#pragma unroll
    for (int i = 0; i < 4; ++i)
#pragma unroll
        for (int j = 0; j < 4; ++j)
#pragma unroll
            for (int r = 0; r < 4; ++r) {
                int m = blockIdx.y * 128 + wm * 64 + i * 16 + kg * 4 + r;
                int n = blockIdx.x * 128 + wn * 64 + j * 16 + lane_m;
                epi.store(m, n, acc[i][j][r]);
            }
}

// --------------------------- depthwise conv + SiLU -------------------------

__global__ __launch_bounds__(256) void conv_silu(const _Float16* __restrict__ xi_raw,
                                                 const float* __restrict__ conv_w,
                                                 const float* __restrict__ conv_b,
                                                 _Float16* __restrict__ xi_out) {
    long t = (long)blockIdx.x * 256 + threadIdx.x;   // one thread per 8 channels
    int  d8 = (int)(t & 255);                        // 2048/8 groups
    long row = t >> 8;                               // token 0..16383
    int  b = (int)(row >> 12);
    int  l = (int)(row & 4095);
    int  d0 = d8 * 8;

    float acc[8];
#pragma unroll
    for (int e = 0; e < 8; ++e) acc[e] = conv_b[d0 + e];
#pragma unroll
    for (int j = 0; j < 4; ++j) {
        int ls = l - 3 + j;
        if (ls >= 0) {
            half8 v = *(const half8*)&xi_raw[((long)b * LSEQ + ls) * DI + d0];
#pragma unroll
            for (int e = 0; e < 8; ++e)
                acc[e] = fmaf((float)v[e], conv_w[(d0 + e) * 4 + j], acc[e]);
        }
    }
    half8 o;
#pragma unroll
    for (int e = 0; e < 8; ++e) {
        float s = acc[e];
        o[e] = (_Float16)(s / (1.f + __expf(-s)));
    }
    *(half8*)&xi_out[row * DI + d0] = o;
}

// ------------------------------ selective scan -----------------------------
// Block = 256 threads = 16 channels x 16 states. One block owns 16 d-channels
// of one batch; loops l = 0..4095 sequentially. h in fp32 registers.

__global__ __launch_bounds__(256) void scan_kernel(const _Float16* __restrict__ dt,
                                                   const _Float16* __restrict__ xi,
                                                   const _Float16* __restrict__ z,
                                                   const float* __restrict__ BC,
                                                   const float* __restrict__ A_log,
                                                   const float* __restrict__ D_param,
                                                   _Float16* __restrict__ y) {
    int bx = blockIdx.x;            // 0..511
    int b  = bx >> 7;               // batch
    int d0 = (bx & 127) << 4;       // 16 channels per block
    int tid = threadIdx.x;
    int ch = tid >> 4;
    int n  = tid & 15;
    int d  = d0 + ch;

    float An = -__expf(A_log[d * DSTATE + n]);
    float Dd = D_param[d];
    float h = 0.f;

    long row = (long)b * LSEQ;
    float dtv = (float)dt[row * DI + d];
    float xv  = (float)xi[row * DI + d];
    float Bn  = BC[row * 32 + n];
    float Cn  = BC[row * 32 + 16 + n];

    for (int l = 0; l < LSEQ; ++l) {
        float dtn = 0.f, xn = 0.f, Bnn = 0.f, Cnn = 0.f;
        if (l + 1 < LSEQ) {     // prefetch next step to hide load latency
            long r2 = row + 1;
            dtn = (float)dt[r2 * DI + d];
            xn  = (float)xi[r2 * DI + d];
            Bnn = BC[r2 * 32 + n];
            Cnn = BC[r2 * 32 + 16 + n];
        }
        float dA = __expf(dtv * An);
        h = fmaf(dA, h, dtv * xv * Bn);
        float yp = h * Cn;
        yp += __shfl_xor(yp, 1, 16);
        yp += __shfl_xor(yp, 2, 16);
        yp += __shfl_xor(yp, 4, 16);
        yp += __shfl_xor(yp, 8, 16);
        if (n == 0) {
            float zv = (float)z[row * DI + d];
            float g  = zv / (1.f + __expf(-zv));
            y[row * DI + d] = (_Float16)((yp + xv * Dd) * g);  // y aliases z: same-index RAW within this thread only
        }
        dtv = dtn; xv = xn; Bn = Bnn; Cn = Cnn;
        ++row;
    }
}

// ------------------------------ launch -------------------------------------

extern "C" void kernel_launch(void* const* d_in, const int* in_sizes, int n_in,
                              void* d_out, int out_size, void* d_ws, size_t ws_size,
                              hipStream_t stream) {
    const float* x       = (const float*)d_in[0];
    const float* W_in    = (const float*)d_in[1];
    const float* conv_w  = (const float*)d_in[2];
    const float* conv_b  = (const float*)d_in[3];
    const float* W_xproj = (const float*)d_in[4];
    const float* W_dt    = (const float*)d_in[5];
    const float* b_dt    = (const float*)d_in[6];
    const float* A_log   = (const float*)d_in[7];
    const float* D_param = (const float*)d_in[8];
    const float* W_out   = (const float*)d_in[9];
    float* out = (float*)d_out;

    char* w = (char*)d_ws;
    size_t off = 0;
    auto alloc = [&](size_t bytes) {
        void* p = w + off;
        off += (bytes + 255) & ~(size_t)255;
        return p;
    };
    _Float16* x_h    = (_Float16*)alloc((size_t)NTOK * DM * 2);     // 32 MB
    _Float16* Win_h  = (_Float16*)alloc((size_t)2 * DI * DM * 2);   // 8 MB
    _Float16* Wout_h = (_Float16*)alloc((size_t)DM * DI * 2);       // 4 MB
    _Float16* Wxp_h  = (_Float16*)alloc((size_t)128 * DI * 2);      // 0.5 MB (padded 96->128)
    _Float16* Wdt_h  = (_Float16*)alloc((size_t)DI * DTR * 2);      // 0.25 MB
    _Float16* xi_raw = (_Float16*)alloc((size_t)NTOK * DI * 2);     // 64 MB (reused as dt)
    _Float16* z_h    = (_Float16*)alloc((size_t)NTOK * DI * 2);     // 64 MB (reused as y)
    _Float16* xi_h   = (_Float16*)alloc((size_t)NTOK * DI * 2);     // 64 MB
    _Float16* dtlo_h = (_Float16*)alloc((size_t)NTOK * DTR * 2);    // 2 MB
    float*    BC     = (float*)alloc((size_t)NTOK * 32 * 4);        // 2 MB
    _Float16* dt_h = xi_raw;   // xi_raw dead after conv (conv runs before GEMM3)
    _Float16* y_h  = z_h;      // scan reads z[i] then writes y[i] in-thread

    // conversions
    cvt_f32_f16<<<(NTOK * DM / 4) / 256, 256, 0, stream>>>(x, x_h, NTOK * DM / 4);
    cvt_f32_f16<<<(2 * DI * DM / 4) / 256, 256, 0, stream>>>(W_in, Win_h, 2 * DI * DM / 4);
    cvt_f32_f16<<<(DM * DI / 4) / 256, 256, 0, stream>>>(W_out, Wout_h, DM * DI / 4);
    cvt_f32_f16<<<(DI * DTR / 4) / 256, 256, 0, stream>>>(W_dt, Wdt_h, DI * DTR / 4);
    cvt_pad_wxp<<<(128 * DI) / 256, 256, 0, stream>>>(W_xproj, Wxp_h);

    // GEMM1: (16384,1024) @ (4096,1024)^T -> split xi / z
    gemm_nt<EpiSplit><<<dim3(2 * DI / 128, NTOK / 128), 256, 0, stream>>>(
        x_h, Win_h, DM, EpiSplit{xi_raw, z_h});

    // causal depthwise conv (k=4) + bias + SiLU
    conv_silu<<<(NTOK * DI / 8) / 256, 256, 0, stream>>>(xi_raw, conv_w, conv_b, xi_h);

    // GEMM2: (16384,2048) @ (96,2048)^T -> dt_lo (f16) + B/C (f32)
    gemm_nt<EpiXproj><<<dim3(1, NTOK / 128), 256, 0, stream>>>(
        xi_h, Wxp_h, DI, EpiXproj{dtlo_h, BC});

    // GEMM3: (16384,64) @ (2048,64)^T + b_dt -> softplus -> dt (f16)
    gemm_nt<EpiDt><<<dim3(DI / 128, NTOK / 128), 256, 0, stream>>>(
        dtlo_h, Wdt_h, DTR, EpiDt{b_dt, dt_h});

    // selective scan + gating -> y (f16)
    scan_kernel<<<BSZ * (DI / 16), 256, 0, stream>>>(
        dt_h, xi_h, z_h, BC, A_log, D_param, y_h);

    // GEMM4: (16384,2048) @ (1024,2048)^T -> out (f32)
    gemm_nt<EpiOut><<<dim3(DM / 128, NTOK / 128), 256, 0, stream>>>(
        y_h, Wout_h, DI, EpiOut{out});
}

// Round 2
// 1662.778 us; speedup vs baseline: 1.9620x; 1.9620x over previous
//
#include <hip/hip_runtime.h>

// ---------------------------------------------------------------------------
// SelectiveSSM (Mamba block) forward on MI355X / gfx950.
// Pipeline: cvt(fp32->fp16) -> GEMM1 (x@W_in^T, split xi/z) -> causal depthwise
// conv+SiLU -> GEMM2 (xi@W_xproj^T, split dt_lo/B/C) -> GEMM3 (dt_lo@W_dt^T +
// b_dt, softplus) -> sequential selective scan + gating -> GEMM4 (y@W_out^T).
// GEMMs: fp16 MFMA 16x16x32, 128x128 tile, BK=32, m97-style K loop.
// Scan: chunked double-buffered LDS pipeline (T=64 steps/chunk).
// ---------------------------------------------------------------------------

#define DM   1024
#define DI   2048
#define DSTATE 16
#define DTR  64
#define BSZ  4
#define LSEQ 4096
#define NTOK (BSZ * LSEQ)   // 16384
#define SCAN_T 64           // steps per LDS chunk

typedef _Float16 half8 __attribute__((ext_vector_type(8)));
typedef _Float16 half4v __attribute__((ext_vector_type(4)));
typedef float f32x4 __attribute__((ext_vector_type(4)));

__device__ __forceinline__ void load_lds16(const _Float16* g, _Float16* l) {
    __builtin_amdgcn_global_load_lds(
        (const __attribute__((address_space(1))) void*)g,
        (__attribute__((address_space(3))) void*)l,
        16, 0, 0);
}

// ------------------------------ conversions --------------------------------

__global__ __launch_bounds__(256) void cvt_f32_f16(const float* __restrict__ in,
                                                   _Float16* __restrict__ out,
                                                   long nvec) {
    long i = (long)blockIdx.x * 256 + threadIdx.x;
    if (i >= nvec) return;
    f32x4 v = ((const f32x4*)in)[i];
    half4v o;
    o[0] = (_Float16)v[0]; o[1] = (_Float16)v[1];
    o[2] = (_Float16)v[2]; o[3] = (_Float16)v[3];
    ((half4v*)out)[i] = o;
}

// W_xproj is (96, 2048); pad to (128, 2048) with zeros so the GEMM N-tile is full.
__global__ __launch_bounds__(256) void cvt_pad_wxp(const float* __restrict__ in,
                                                   _Float16* __restrict__ out) {
    int i = blockIdx.x * 256 + threadIdx.x;   // over 128*2048
    int row = i >> 11;
    int col = i & 2047;
    out[i] = (row < 96) ? (_Float16)in[row * 2048 + col] : (_Float16)0.f;
}

// ------------------------------ GEMM (NT) ----------------------------------
// C[m,n] = sum_k A[m,k] * B[n,k].  A: (M,K) fp16 row-major. B: (N,K) fp16
// row-major. 128x128 tile, BK=32, 256 threads (4 waves, 2x2 wave grid, each
// wave 64x64 = 4x4 MFMA 16x16x32 tiles). Epilogue via functor.

struct EpiSplit {          // GEMM1: n<2048 -> xi_raw(f16), else z(f16)
    _Float16* xi; _Float16* z;
    __device__ void store(int m, int n, float v) const {
        if (n < DI) xi[(long)m * DI + n] = (_Float16)v;
        else        z[(long)m * DI + (n - DI)] = (_Float16)v;
    }
};
struct EpiXproj {          // GEMM2: n<64 -> dt_lo(f16); 64..95 -> BC(f32)
    _Float16* dtlo; float* BC;
    __device__ void store(int m, int n, float v) const {
        if (n < DTR)      dtlo[(long)m * DTR + n] = (_Float16)v;
        else if (n < 96)  BC[(long)m * 32 + (n - DTR)] = v;
    }
};
struct EpiDt {             // GEMM3: softplus(v + b_dt[n]) -> dt(f16)
    const float* b_dt; _Float16* dt;
    __device__ void store(int m, int n, float v) const {
        float t = v + b_dt[n];
        float sp = (t > 20.f) ? t : log1pf(__expf(t));
        dt[(long)m * DI + n] = (_Float16)sp;
    }
};
struct EpiOut {            // GEMM4: plain fp32 store
    float* out;
    __device__ void store(int m, int n, float v) const {
        out[(long)m * DM + n] = v;
    }
};

template <class Epi>
__global__ __launch_bounds__(256, 2) void gemm_nt(const _Float16* __restrict__ A,
                                                  const _Float16* __restrict__ B,
                                                  int K, Epi epi) {
    __shared__ __align__(16) _Float16 As[128 * 32];
    __shared__ __align__(16) _Float16 Bs[128 * 32];
    const int tid  = threadIdx.x;
    const int wave = tid >> 6;
    const int ln   = tid & 63;
    const int wm   = wave & 1;      // 2x2 wave grid over the 128x128 tile
    const int wn   = wave >> 1;
    const int lane_m = ln & 15;     // MFMA A/B operand: row/col = lane&15
    const int kg     = ln >> 4;     // k-group: 8 halves each

    const long Abase = (long)blockIdx.y * 128 * K;
    const long Bbase = (long)blockIdx.x * 128 * K;

    f32x4 acc[4][4];
#pragma unroll
    for (int i = 0; i < 4; ++i)
#pragma unroll
        for (int j = 0; j < 4; ++j) acc[i][j] = (f32x4){0.f, 0.f, 0.f, 0.f};

    for (int k0 = 0; k0 < K; k0 += 32) {
        __syncthreads();   // protect LDS from previous iteration's readers
#pragma unroll
        for (int c = 0; c < 2; ++c) {
            int lin = tid + c * 256;           // 0..511
            int row = lin >> 2;                // 128 rows
            int col = (lin & 3) << 3;          // 4 chunks of 8 halves
            load_lds16(A + Abase + (long)row * K + k0 + col,
                       As + (size_t)(wave * 64 + c * 256) * 8);
            load_lds16(B + Bbase + (long)row * K + k0 + col,
                       Bs + (size_t)(wave * 64 + c * 256) * 8);
        }
        asm volatile("s_waitcnt vmcnt(0)" ::: "memory");
        __syncthreads();

        half8 a[4], b[4];
#pragma unroll
        for (int i = 0; i < 4; ++i)
            a[i] = *(const half8*)&As[(wm * 64 + i * 16 + lane_m) * 32 + kg * 8];
#pragma unroll
        for (int j = 0; j < 4; ++j)
            b[j] = *(const half8*)&Bs[(wn * 64 + j * 16 + lane_m) * 32 + kg * 8];
#pragma unroll
        for (int i = 0; i < 4; ++i)
#pragma unroll
            for (int j = 0; j < 4; ++j)
                acc[i][j] = __builtin_amdgcn_mfma_f32_16x16x32_f16(a[i], b[j], acc[i][j], 0, 0, 0);
    }

    // C/D layout: row m = (lane>>4)*4 + reg, col n = lane&15  (verified m89)
#pragma unroll
    for (int i = 0; i < 4; ++i)
#pragma unroll
        for (int j = 0; j < 4; ++j)
#pragma unroll
            for (int r = 0; r < 4; ++r) {
                int m = blockIdx.y * 128 + wm * 64 + i * 16 + kg * 4 + r;
                int n = blockIdx.x * 128 + wn * 64 + j * 16 + lane_m;
                epi.store(m, n, acc[i][j][r]);
            }
}

// --------------------------- depthwise conv + SiLU -------------------------

__global__ __launch_bounds__(256) void conv_silu(const _Float16* __restrict__ xi_raw,
                                                 const float* __restrict__ conv_w,
                                                 const float* __restrict__ conv_b,
                                                 _Float16* __restrict__ xi_out) {
    long t = (long)blockIdx.x * 256 + threadIdx.x;   // one thread per 8 channels
    int  d8 = (int)(t & 255);                        // 2048/8 groups
    long row = t >> 8;                               // token 0..16383
    int  b = (int)(row >> 12);
    int  l = (int)(row & 4095);
    int  d0 = d8 * 8;

    float acc[8];
#pragma unroll
    for (int e = 0; e < 8; ++e) acc[e] = conv_b[d0 + e];
#pragma unroll
    for (int j = 0; j < 4; ++j) {
        int ls = l - 3 + j;
        if (ls >= 0) {
            half8 v = *(const half8*)&xi_raw[((long)b * LSEQ + ls) * DI + d0];
#pragma unroll
            for (int e = 0; e < 8; ++e)
                acc[e] = fmaf((float)v[e], conv_w[(d0 + e) * 4 + j], acc[e]);
        }
    }
    half8 o;
#pragma unroll
    for (int e = 0; e < 8; ++e) {
        float s = acc[e];
        o[e] = (_Float16)(s / (1.f + __expf(-s)));
    }
    *(half8*)&xi_out[row * DI + d0] = o;
}

// ------------------------------ selective scan -----------------------------
// Block = 256 threads = 16 channels x 16 states; one block owns 16 d-channels
// of one batch. Sequence processed in chunks of SCAN_T steps staged through
// double-buffered LDS (coalesced vector global loads), so the serial loop
// runs entirely out of LDS. Gated output staged in LDS, stored per chunk.

__global__ __launch_bounds__(256) void scan_kernel(const _Float16* __restrict__ dt,
                                                   const _Float16* __restrict__ xi,
                                                   const _Float16* __restrict__ z,
                                                   const float* __restrict__ BC,
                                                   const float* __restrict__ A_log,
                                                   const float* __restrict__ D_param,
                                                   _Float16* __restrict__ y) {
    __shared__ float ddx[2][SCAN_T][16][2];  // [dt, dt*x] per (t, ch)   16 KB
    __shared__ float bcs[2][SCAN_T][16][2];  // [B, C]    per (t, n)     16 KB
    __shared__ float xds[2][SCAN_T][16];     // x*D       per (t, ch)     8 KB
    __shared__ float zgs[2][SCAN_T][16];     // silu(z)   per (t, ch)     8 KB
    __shared__ float ybuf[SCAN_T][16];       // scan out  per (t, ch)     4 KB

    const int bx = blockIdx.x;            // 0..511
    const int b  = bx >> 7;               // batch
    const int d0 = (bx & 127) << 4;       // 16 channels per block
    const int tid = threadIdx.x;
    const int ch = tid >> 4;              // compute role: channel
    const int n  = tid & 15;              // compute role: state index
    const int d  = d0 + ch;
    const int sr = tid >> 2;              // staging role: row 0..63
    const int sg = tid & 3;               // staging role: 4-channel group
    const int c0 = sg * 4;

    const float An = -__expf(A_log[d * DSTATE + n]);
    const f32x4 Dv = *(const f32x4*)&D_param[d0 + c0];
    float h = 0.f;
    const long base = (long)b * LSEQ;

    half4v rdt, rxi, rz; f32x4 rb0, rb1;
    auto stage_load = [&](int l0) {
        long r = base + l0 + sr;
        rdt = *(const half4v*)&dt[r * DI + d0 + c0];
        rxi = *(const half4v*)&xi[r * DI + d0 + c0];
        rz  = *(const half4v*)&z [r * DI + d0 + c0];
        rb0 = *(const f32x4*)&BC[r * 32 + sg * 8];
        rb1 = *(const f32x4*)&BC[r * 32 + sg * 8 + 4];
    };
    auto stage_write = [&](int buf) {
#pragma unroll
        for (int e = 0; e < 4; ++e) {
            float dtf = (float)rdt[e], xf = (float)rxi[e], zf = (float)rz[e];
            ddx[buf][sr][c0 + e][0] = dtf;
            ddx[buf][sr][c0 + e][1] = dtf * xf;
            xds[buf][sr][c0 + e] = xf * Dv[e];
            zgs[buf][sr][c0 + e] = zf / (1.f + __expf(-zf));
        }
#pragma unroll
        for (int e = 0; e < 8; ++e) {
            float v = (e < 4) ? rb0[e] : rb1[e - 4];
            int col = sg * 8 + e;               // 0..31 within BC row
            if (col < 16) bcs[buf][sr][col][0] = v;       // B
            else          bcs[buf][sr][col - 16][1] = v;  // C
        }
    };

    stage_load(0);
    stage_write(0);
    stage_load(SCAN_T);
    __syncthreads();

    const int NCH = LSEQ / SCAN_T;
    for (int c = 0; c < NCH; ++c) {
        const int cur = c & 1;
#pragma unroll 4
        for (int t = 0; t < SCAN_T; ++t) {
            float ddt = ddx[cur][t][ch][0];
            float dxv = ddx[cur][t][ch][1];
            float Bn  = bcs[cur][t][n][0];
            float Cn  = bcs[cur][t][n][1];
            float dA = __expf(ddt * An);
            h = fmaf(dA, h, dxv * Bn);
            float yp = h * Cn;
            yp += __shfl_xor(yp, 1, 16);
            yp += __shfl_xor(yp, 2, 16);
            yp += __shfl_xor(yp, 4, 16);
            yp += __shfl_xor(yp, 8, 16);
            if (n == 0) ybuf[t][ch] = yp;
        }
        __syncthreads();   // ybuf complete; everyone done reading buf[cur]

        {   // epilogue: gated output for chunk c, coalesced f16 store
            long r = base + (long)c * SCAN_T + sr;
            half4v o;
#pragma unroll
            for (int e = 0; e < 4; ++e)
                o[e] = (_Float16)((ybuf[sr][c0 + e] + xds[cur][sr][c0 + e]) *
                                  zgs[cur][sr][c0 + e]);
            *(half4v*)&y[r * DI + d0 + c0] = o;
        }
        if (c + 1 < NCH) {
            stage_write(cur ^ 1);                       // regs -> next buffer
            if (c + 2 < NCH) stage_load((c + 2) * SCAN_T);  // prefetch
        }
        __syncthreads();   // buf[nxt] visible before next compute
    }
}

// ------------------------------ launch -------------------------------------

extern "C" void kernel_launch(void* const* d_in, const int* in_sizes, int n_in,
                              void* d_out, int out_size, void* d_ws, size_t ws_size,
                              hipStream_t stream) {
    const float* x       = (const float*)d_in[0];
    const float* W_in    = (const float*)d_in[1];
    const float* conv_w  = (const float*)d_in[2];
    const float* conv_b  = (const float*)d_in[3];
    const float* W_xproj = (const float*)d_in[4];
    const float* W_dt    = (const float*)d_in[5];
    const float* b_dt    = (const float*)d_in[6];
    const float* A_log   = (const float*)d_in[7];
    const float* D_param = (const float*)d_in[8];
    const float* W_out   = (const float*)d_in[9];
    float* out = (float*)d_out;

    char* w = (char*)d_ws;
    size_t off = 0;
    auto alloc = [&](size_t bytes) {
        void* p = w + off;
        off += (bytes + 255) & ~(size_t)255;
        return p;
    };
    _Float16* x_h    = (_Float16*)alloc((size_t)NTOK * DM * 2);     // 32 MB
    _Float16* Win_h  = (_Float16*)alloc((size_t)2 * DI * DM * 2);   // 8 MB
    _Float16* Wout_h = (_Float16*)alloc((size_t)DM * DI * 2);       // 4 MB
    _Float16* Wxp_h  = (_Float16*)alloc((size_t)128 * DI * 2);      // 0.5 MB (padded 96->128)
    _Float16* Wdt_h  = (_Float16*)alloc((size_t)DI * DTR * 2);      // 0.25 MB
    _Float16* xi_raw = (_Float16*)alloc((size_t)NTOK * DI * 2);     // 64 MB (reused as dt)
    _Float16* z_h    = (_Float16*)alloc((size_t)NTOK * DI * 2);     // 64 MB (reused as y)
    _Float16* xi_h   = (_Float16*)alloc((size_t)NTOK * DI * 2);     // 64 MB
    _Float16* dtlo_h = (_Float16*)alloc((size_t)NTOK * DTR * 2);    // 2 MB
    float*    BC     = (float*)alloc((size_t)NTOK * 32 * 4);        // 2 MB
    _Float16* dt_h = xi_raw;   // xi_raw dead after conv (conv runs before GEMM3)
    _Float16* y_h  = z_h;      // scan: y-stores always behind z-reads (rows increase)

    // conversions
    cvt_f32_f16<<<(NTOK * DM / 4) / 256, 256, 0, stream>>>(x, x_h, NTOK * DM / 4);
    cvt_f32_f16<<<(2 * DI * DM / 4) / 256, 256, 0, stream>>>(W_in, Win_h, 2 * DI * DM / 4);
    cvt_f32_f16<<<(DM * DI / 4) / 256, 256, 0, stream>>>(W_out, Wout_h, DM * DI / 4);
    cvt_f32_f16<<<(DI * DTR / 4) / 256, 256, 0, stream>>>(W_dt, Wdt_h, DI * DTR / 4);
    cvt_pad_wxp<<<(128 * DI) / 256, 256, 0, stream>>>(W_xproj, Wxp_h);

    // GEMM1: (16384,1024) @ (4096,1024)^T -> split xi / z
    gemm_nt<EpiSplit><<<dim3(2 * DI / 128, NTOK / 128), 256, 0, stream>>>(
        x_h, Win_h, DM, EpiSplit{xi_raw, z_h});

    // causal depthwise conv (k=4) + bias + SiLU
    conv_silu<<<(NTOK * DI / 8) / 256, 256, 0, stream>>>(xi_raw, conv_w, conv_b, xi_h);

    // GEMM2: (16384,2048) @ (96,2048)^T -> dt_lo (f16) + B/C (f32)
    gemm_nt<EpiXproj><<<dim3(1, NTOK / 128), 256, 0, stream>>>(
        xi_h, Wxp_h, DI, EpiXproj{dtlo_h, BC});

    // GEMM3: (16384,64) @ (2048,64)^T + b_dt -> softplus -> dt (f16)
    gemm_nt<EpiDt><<<dim3(DI / 128, NTOK / 128), 256, 0, stream>>>(
        dtlo_h, Wdt_h, DTR, EpiDt{b_dt, dt_h});

    // selective scan + gating -> y (f16)
    scan_kernel<<<BSZ * (DI / 16), 256, 0, stream>>>(
        dt_h, xi_h, z_h, BC, A_log, D_param, y_h);

    // GEMM4: (16384,2048) @ (1024,2048)^T -> out (f32)
    gemm_nt<EpiOut><<<dim3(DM / 128, NTOK / 128), 256, 0, stream>>>(
        y_h, Wout_h, DI, EpiOut{out});
}

// Round 4
// 1026.850 us; speedup vs baseline: 3.1770x; 1.6193x over previous
//
#include <hip/hip_runtime.h>

// ---------------------------------------------------------------------------
// SelectiveSSM (Mamba block) forward on MI355X / gfx950.
// Pipeline: cvt(fp32->fp16) -> GEMM1 (x@W_in^T, split xi/z) -> causal depthwise
// conv+SiLU -> GEMM2 (xi@W_xproj^T, split dt_lo/B/C) -> GEMM3 (dt_lo@W_dt^T +
// b_dt, softplus) -> 3-phase chunked parallel selective scan -> GEMM4.
// GEMMs: fp16 MFMA 16x16x32, 128x128 tile, BK=32, m97-style K loop.
// Scan: affine-map segment composition; each lane owns 16 states in regs.
// Workspace budget ~241 MB: P/H segment buffers alias the dead x_h/Win_h
// region (contiguous 40 MB); hin aliases P in-place (read-before-write).
// ---------------------------------------------------------------------------

#define DM   1024
#define DI   2048
#define DSTATE 16
#define DTR  64
#define BSZ  4
#define LSEQ 4096
#define NTOK (BSZ * LSEQ)   // 16384
#define NSEG 32             // segments per sequence (parallel scan)
#define SEG  (LSEQ / NSEG)  // 128 steps per segment
#define CT   8              // register-staged steps per sub-chunk

typedef _Float16 half8 __attribute__((ext_vector_type(8)));
typedef _Float16 half4v __attribute__((ext_vector_type(4)));
typedef float f32x4 __attribute__((ext_vector_type(4)));

__device__ __forceinline__ void load_lds16(const _Float16* g, _Float16* l) {
    __builtin_amdgcn_global_load_lds(
        (const __attribute__((address_space(1))) void*)g,
        (__attribute__((address_space(3))) void*)l,
        16, 0, 0);
}

// ------------------------------ conversions --------------------------------

__global__ __launch_bounds__(256) void cvt_f32_f16(const float* __restrict__ in,
                                                   _Float16* __restrict__ out,
                                                   long nvec) {
    long i = (long)blockIdx.x * 256 + threadIdx.x;
    if (i >= nvec) return;
    f32x4 v = ((const f32x4*)in)[i];
    half4v o;
    o[0] = (_Float16)v[0]; o[1] = (_Float16)v[1];
    o[2] = (_Float16)v[2]; o[3] = (_Float16)v[3];
    ((half4v*)out)[i] = o;
}

// W_xproj is (96, 2048); pad to (128, 2048) with zeros so the GEMM N-tile is full.
__global__ __launch_bounds__(256) void cvt_pad_wxp(const float* __restrict__ in,
                                                   _Float16* __restrict__ out) {
    int i = blockIdx.x * 256 + threadIdx.x;   // over 128*2048
    int row = i >> 11;
    int col = i & 2047;
    out[i] = (row < 96) ? (_Float16)in[row * 2048 + col] : (_Float16)0.f;
}

// ------------------------------ GEMM (NT) ----------------------------------
// C[m,n] = sum_k A[m,k] * B[n,k].  A: (M,K) fp16 row-major. B: (N,K) fp16
// row-major. 128x128 tile, BK=32, 256 threads (4 waves, 2x2 wave grid, each
// wave 64x64 = 4x4 MFMA 16x16x32 tiles). Epilogue via functor.

struct EpiSplit {          // GEMM1: n<2048 -> xi_raw(f16), else z(f16)
    _Float16* xi; _Float16* z;
    __device__ void store(int m, int n, float v) const {
        if (n < DI) xi[(long)m * DI + n] = (_Float16)v;
        else        z[(long)m * DI + (n - DI)] = (_Float16)v;
    }
};
struct EpiXproj {          // GEMM2: n<64 -> dt_lo(f16); 64..95 -> BC(f32)
    _Float16* dtlo; float* BC;
    __device__ void store(int m, int n, float v) const {
        if (n < DTR)      dtlo[(long)m * DTR + n] = (_Float16)v;
        else if (n < 96)  BC[(long)m * 32 + (n - DTR)] = v;
    }
};
struct EpiDt {             // GEMM3: softplus(v + b_dt[n]) -> dt(f16)
    const float* b_dt; _Float16* dt;
    __device__ void store(int m, int n, float v) const {
        float t = v + b_dt[n];
        float sp = (t > 20.f) ? t : log1pf(__expf(t));
        dt[(long)m * DI + n] = (_Float16)sp;
    }
};
struct EpiOut {            // GEMM4: plain fp32 store
    float* out;
    __device__ void store(int m, int n, float v) const {
        out[(long)m * DM + n] = v;
    }
};

template <class Epi>
__global__ __launch_bounds__(256, 2) void gemm_nt(const _Float16* __restrict__ A,
                                                  const _Float16* __restrict__ B,
                                                  int K, Epi epi) {
    __shared__ __align__(16) _Float16 As[128 * 32];
    __shared__ __align__(16) _Float16 Bs[128 * 32];
    const int tid  = threadIdx.x;
    const int wave = tid >> 6;
    const int ln   = tid & 63;
    const int wm   = wave & 1;      // 2x2 wave grid over the 128x128 tile
    const int wn   = wave >> 1;
    const int lane_m = ln & 15;     // MFMA A/B operand: row/col = lane&15
    const int kg     = ln >> 4;     // k-group: 8 halves each

    const long Abase = (long)blockIdx.y * 128 * K;
    const long Bbase = (long)blockIdx.x * 128 * K;

    f32x4 acc[4][4];
#pragma unroll
    for (int i = 0; i < 4; ++i)
#pragma unroll
        for (int j = 0; j < 4; ++j) acc[i][j] = (f32x4){0.f, 0.f, 0.f, 0.f};

    for (int k0 = 0; k0 < K; k0 += 32) {
        __syncthreads();   // protect LDS from previous iteration's readers
#pragma unroll
        for (int c = 0; c < 2; ++c) {
            int lin = tid + c * 256;           // 0..511
            int row = lin >> 2;                // 128 rows
            int col = (lin & 3) << 3;          // 4 chunks of 8 halves
            load_lds16(A + Abase + (long)row * K + k0 + col,
                       As + (size_t)(wave * 64 + c * 256) * 8);
            load_lds16(B + Bbase + (long)row * K + k0 + col,
                       Bs + (size_t)(wave * 64 + c * 256) * 8);
        }
        asm volatile("s_waitcnt vmcnt(0)" ::: "memory");
        __syncthreads();

        half8 a[4], b[4];
#pragma unroll
        for (int i = 0; i < 4; ++i)
            a[i] = *(const half8*)&As[(wm * 64 + i * 16 + lane_m) * 32 + kg * 8];
#pragma unroll
        for (int j = 0; j < 4; ++j)
            b[j] = *(const half8*)&Bs[(wn * 64 + j * 16 + lane_m) * 32 + kg * 8];
#pragma unroll
        for (int i = 0; i < 4; ++i)
#pragma unroll
            for (int j = 0; j < 4; ++j)
                acc[i][j] = __builtin_amdgcn_mfma_f32_16x16x32_f16(a[i], b[j], acc[i][j], 0, 0, 0);
    }

    // C/D layout: row m = (lane>>4)*4 + reg, col n = lane&15  (verified m89)
#pragma unroll
    for (int i = 0; i < 4; ++i)
#pragma unroll
        for (int j = 0; j < 4; ++j)
#pragma unroll
            for (int r = 0; r < 4; ++r) {
                int m = blockIdx.y * 128 + wm * 64 + i * 16 + kg * 4 + r;
                int n = blockIdx.x * 128 + wn * 64 + j * 16 + lane_m;
                epi.store(m, n, acc[i][j][r]);
            }
}

// --------------------------- depthwise conv + SiLU -------------------------

__global__ __launch_bounds__(256) void conv_silu(const _Float16* __restrict__ xi_raw,
                                                 const float* __restrict__ conv_w,
                                                 const float* __restrict__ conv_b,
                                                 _Float16* __restrict__ xi_out) {
    long t = (long)blockIdx.x * 256 + threadIdx.x;   // one thread per 8 channels
    int  d8 = (int)(t & 255);                        // 2048/8 groups
    long row = t >> 8;                               // token 0..16383
    int  b = (int)(row >> 12);
    int  l = (int)(row & 4095);
    int  d0 = d8 * 8;

    float acc[8];
#pragma unroll
    for (int e = 0; e < 8; ++e) acc[e] = conv_b[d0 + e];
#pragma unroll
    for (int j = 0; j < 4; ++j) {
        int ls = l - 3 + j;
        if (ls >= 0) {
            half8 v = *(const half8*)&xi_raw[((long)b * LSEQ + ls) * DI + d0];
#pragma unroll
            for (int e = 0; e < 8; ++e)
                acc[e] = fmaf((float)v[e], conv_w[(d0 + e) * 4 + j], acc[e]);
        }
    }
    half8 o;
#pragma unroll
    for (int e = 0; e < 8; ++e) {
        float s = acc[e];
        o[e] = (_Float16)(s / (1.f + __expf(-s)));
    }
    *(half8*)&xi_out[row * DI + d0] = o;
}

// ------------------------- parallel selective scan -------------------------
// h_t = dA_t * h_{t-1} + (dt*x)_t * B_t  is an affine map in h; segments
// compose: out = P*in + H with P = prod(dA), H = local scan from h=0.
// part1: per (b, d-lane, seg) compute P[16], H[16].           (no LDS)
// part2: per (b, d, n) serial scan over NSEG segments -> hin (in-place on P).
// part3: replay each segment from hin, produce gated y.       (no LDS)

__global__ __launch_bounds__(256) void scan_part1(const _Float16* __restrict__ dt,
                                                  const _Float16* __restrict__ xi,
                                                  const float* __restrict__ BC,
                                                  const float* __restrict__ A_log,
                                                  float* __restrict__ Pout,
                                                  float* __restrict__ Hout) {
    const int d   = blockIdx.x * 256 + threadIdx.x;
    const int seg = blockIdx.y;
    const int b   = blockIdx.z;

    float A[16], P[16], h[16];
#pragma unroll
    for (int n = 0; n < 16; ++n) {
        A[n] = -__expf(A_log[d * DSTATE + n]);
        P[n] = 1.f;
        h[n] = 0.f;
    }
    const long t0 = (long)b * LSEQ + (long)seg * SEG;
    const _Float16* dp = dt + t0 * DI + d;
    const _Float16* xp = xi + t0 * DI + d;
    const float*    bp = BC + t0 * 32;

    for (int cc = 0; cc < SEG / CT; ++cc) {
        _Float16 ldt[CT], lx[CT];
#pragma unroll
        for (int j = 0; j < CT; ++j) {           // independent coalesced loads
            long o = (long)(cc * CT + j) * DI;
            ldt[j] = dp[o];
            lx[j]  = xp[o];
        }
#pragma unroll
        for (int j = 0; j < CT; ++j) {
            const float* row = bp + (cc * CT + j) * 32;
            f32x4 Bq[4];
#pragma unroll
            for (int q = 0; q < 4; ++q) Bq[q] = *(const f32x4*)(row + q * 4);
            float dtf = (float)ldt[j];
            float u   = dtf * (float)lx[j];
#pragma unroll
            for (int n = 0; n < 16; ++n) {
                float dA = __expf(dtf * A[n]);
                P[n] *= dA;
                h[n] = fmaf(dA, h[n], u * Bq[n >> 2][n & 3]);
            }
        }
    }
    float* po = Pout + (((long)b * NSEG + seg) * DI + d) * 16;
    float* ho = Hout + (((long)b * NSEG + seg) * DI + d) * 16;
#pragma unroll
    for (int q = 0; q < 4; ++q) {
        *(f32x4*)(po + q * 4) = (f32x4){P[q*4], P[q*4+1], P[q*4+2], P[q*4+3]};
        *(f32x4*)(ho + q * 4) = (f32x4){h[q*4], h[q*4+1], h[q*4+2], h[q*4+3]};
    }
}

// NOTE: hin aliases P (in-place). Per-thread: P[idx]/H[idx] are loaded into
// registers BEFORE hin[idx] is stored; each idx is touched by exactly one
// thread. No __restrict__ here so the compiler respects the aliasing.
__global__ __launch_bounds__(256) void scan_part2(const float* P,
                                                  const float* H,
                                                  float* hin) {
    long t = (long)blockIdx.x * 256 + threadIdx.x;   // BSZ*DI*16 = 131072
    int  n = (int)(t & 15);
    long d = (t >> 4) & (DI - 1);
    int  b = (int)(t >> 15);
    float h = 0.f;
    for (int s = 0; s < NSEG; ++s) {
        long idx = (((long)b * NSEG + s) * DI + d) * 16 + n;
        float p  = P[idx];
        float hh = H[idx];
        hin[idx] = h;                       // state entering segment s
        h = fmaf(p, h, hh);
    }
}

__global__ __launch_bounds__(256) void scan_part3(const _Float16* __restrict__ dt,
                                                  const _Float16* __restrict__ xi,
                                                  const _Float16* z,      // aliases y
                                                  const float* __restrict__ BC,
                                                  const float* __restrict__ A_log,
                                                  const float* __restrict__ D_param,
                                                  const float* __restrict__ hin,
                                                  _Float16* y) {
    const int d   = blockIdx.x * 256 + threadIdx.x;
    const int seg = blockIdx.y;
    const int b   = blockIdx.z;

    float A[16], h[16];
    const float* hi = hin + (((long)b * NSEG + seg) * DI + d) * 16;
#pragma unroll
    for (int n = 0; n < 16; ++n) {
        A[n] = -__expf(A_log[d * DSTATE + n]);
        h[n] = hi[n];
    }
    const float Dd = D_param[d];
    const long t0 = (long)b * LSEQ + (long)seg * SEG;
    const _Float16* dp = dt + t0 * DI + d;
    const _Float16* xp = xi + t0 * DI + d;
    const _Float16* zp = z  + t0 * DI + d;
    _Float16*       yp = y  + t0 * DI + d;
    const float*    bp = BC + t0 * 32;

    for (int cc = 0; cc < SEG / CT; ++cc) {
        _Float16 ldt[CT], lx[CT], lz[CT];
#pragma unroll
        for (int j = 0; j < CT; ++j) {
            long o = (long)(cc * CT + j) * DI;
            ldt[j] = dp[o];
            lx[j]  = xp[o];
            lz[j]  = zp[o];
        }
#pragma unroll
        for (int j = 0; j < CT; ++j) {
            const float* row = bp + (cc * CT + j) * 32;
            f32x4 Bq[4], Cq[4];
#pragma unroll
            for (int q = 0; q < 4; ++q) {
                Bq[q] = *(const f32x4*)(row + q * 4);
                Cq[q] = *(const f32x4*)(row + 16 + q * 4);
            }
            float dtf = (float)ldt[j];
            float xf  = (float)lx[j];
            float u   = dtf * xf;
            float a0 = 0.f, a1 = 0.f, a2 = 0.f, a3 = 0.f;
#pragma unroll
            for (int n = 0; n < 16; ++n) {
                float dA = __expf(dtf * A[n]);
                h[n] = fmaf(dA, h[n], u * Bq[n >> 2][n & 3]);
                float c = Cq[n >> 2][n & 3];
                if ((n & 3) == 0) a0 = fmaf(h[n], c, a0);
                else if ((n & 3) == 1) a1 = fmaf(h[n], c, a1);
                else if ((n & 3) == 2) a2 = fmaf(h[n], c, a2);
                else a3 = fmaf(h[n], c, a3);
            }
            float ys = (a0 + a1) + (a2 + a3);
            float zf = (float)lz[j];
            float g  = zf / (1.f + __expf(-zf));
            yp[(long)(cc * CT + j) * DI] = (_Float16)((ys + xf * Dd) * g);
        }
    }
}

// ------------------------------ launch -------------------------------------

extern "C" void kernel_launch(void* const* d_in, const int* in_sizes, int n_in,
                              void* d_out, int out_size, void* d_ws, size_t ws_size,
                              hipStream_t stream) {
    const float* x       = (const float*)d_in[0];
    const float* W_in    = (const float*)d_in[1];
    const float* conv_w  = (const float*)d_in[2];
    const float* conv_b  = (const float*)d_in[3];
    const float* W_xproj = (const float*)d_in[4];
    const float* W_dt    = (const float*)d_in[5];
    const float* b_dt    = (const float*)d_in[6];
    const float* A_log   = (const float*)d_in[7];
    const float* D_param = (const float*)d_in[8];
    const float* W_out   = (const float*)d_in[9];
    float* out = (float*)d_out;

    char* w = (char*)d_ws;
    size_t off = 0;
    auto alloc = [&](size_t bytes) {
        void* p = w + off;
        off += (bytes + 255) & ~(size_t)255;
        return p;
    };
    // x_h and Win_h are adjacent => contiguous 40 MB region, dead after GEMM1;
    // it hosts Pseg (16.8 MB) + Hseg (16.8 MB) during the scan.
    _Float16* x_h    = (_Float16*)alloc((size_t)NTOK * DM * 2);     // 32 MB
    _Float16* Win_h  = (_Float16*)alloc((size_t)2 * DI * DM * 2);   // 8 MB
    _Float16* Wout_h = (_Float16*)alloc((size_t)DM * DI * 2);       // 4 MB
    _Float16* Wxp_h  = (_Float16*)alloc((size_t)128 * DI * 2);      // 0.5 MB (padded 96->128)
    _Float16* Wdt_h  = (_Float16*)alloc((size_t)DI * DTR * 2);      // 0.25 MB
    _Float16* xi_raw = (_Float16*)alloc((size_t)NTOK * DI * 2);     // 64 MB (reused as dt)
    _Float16* z_h    = (_Float16*)alloc((size_t)NTOK * DI * 2);     // 64 MB (reused as y)
    _Float16* xi_h   = (_Float16*)alloc((size_t)NTOK * DI * 2);     // 64 MB
    _Float16* dtlo_h = (_Float16*)alloc((size_t)NTOK * DTR * 2);    // 2 MB
    float*    BC     = (float*)alloc((size_t)NTOK * 32 * 4);        // 2 MB
    _Float16* dt_h = xi_raw;   // xi_raw dead after conv (conv runs before GEMM3)
    _Float16* y_h  = z_h;      // scan part3: z read staged before y store, same thread
    const size_t seg_bytes = (size_t)BSZ * NSEG * DI * 16 * 4;      // 16.8 MB
    float* Pseg = (float*)x_h;                                      // aliases x_h
    float* Hseg = (float*)((char*)x_h + ((seg_bytes + 255) & ~(size_t)255)); // spills into Win_h
    float* hin  = Pseg;        // part2 overwrites P in place (read-before-write)

    // conversions
    cvt_f32_f16<<<(NTOK * DM / 4) / 256, 256, 0, stream>>>(x, x_h, NTOK * DM / 4);
    cvt_f32_f16<<<(2 * DI * DM / 4) / 256, 256, 0, stream>>>(W_in, Win_h, 2 * DI * DM / 4);
    cvt_f32_f16<<<(DM * DI / 4) / 256, 256, 0, stream>>>(W_out, Wout_h, DM * DI / 4);
    cvt_f32_f16<<<(DI * DTR / 4) / 256, 256, 0, stream>>>(W_dt, Wdt_h, DI * DTR / 4);
    cvt_pad_wxp<<<(128 * DI) / 256, 256, 0, stream>>>(W_xproj, Wxp_h);

    // GEMM1: (16384,1024) @ (4096,1024)^T -> split xi / z
    gemm_nt<EpiSplit><<<dim3(2 * DI / 128, NTOK / 128), 256, 0, stream>>>(
        x_h, Win_h, DM, EpiSplit{xi_raw, z_h});

    // causal depthwise conv (k=4) + bias + SiLU
    conv_silu<<<(NTOK * DI / 8) / 256, 256, 0, stream>>>(xi_raw, conv_w, conv_b, xi_h);

    // GEMM2: (16384,2048) @ (96,2048)^T -> dt_lo (f16) + B/C (f32)
    gemm_nt<EpiXproj><<<dim3(1, NTOK / 128), 256, 0, stream>>>(
        xi_h, Wxp_h, DI, EpiXproj{dtlo_h, BC});

    // GEMM3: (16384,64) @ (2048,64)^T + b_dt -> softplus -> dt (f16)
    gemm_nt<EpiDt><<<dim3(DI / 128, NTOK / 128), 256, 0, stream>>>(
        dtlo_h, Wdt_h, DTR, EpiDt{b_dt, dt_h});

    // parallel selective scan (P/H/hin live in the dead x_h/Win_h region)
    scan_part1<<<dim3(DI / 256, NSEG, BSZ), 256, 0, stream>>>(
        dt_h, xi_h, BC, A_log, Pseg, Hseg);
    scan_part2<<<(BSZ * DI * 16) / 256, 256, 0, stream>>>(Pseg, Hseg, hin);
    scan_part3<<<dim3(DI / 256, NSEG, BSZ), 256, 0, stream>>>(
        dt_h, xi_h, z_h, BC, A_log, D_param, hin, y_h);

    // GEMM4: (16384,2048) @ (1024,2048)^T -> out (f32)
    gemm_nt<EpiOut><<<dim3(DM / 128, NTOK / 128), 256, 0, stream>>>(
        y_h, Wout_h, DI, EpiOut{out});
}

// Round 5
// 881.296 us; speedup vs baseline: 3.7017x; 1.1652x over previous
//
#include <hip/hip_runtime.h>

// ---------------------------------------------------------------------------
// SelectiveSSM (Mamba block) forward on MI355X / gfx950.
// Pipeline: cvt(fp32->fp16) -> GEMM1 (x@W_in^T, split xi/z) -> causal depthwise
// conv+SiLU -> GEMM2 (xi@W_xproj^T, split dt_lo/B/C) -> GEMM3 (dt_lo@W_dt^T +
// b_dt, softplus) -> 3-phase chunked parallel selective scan -> GEMM4.
// GEMMs: fp16 MFMA 16x16x32, 128x128 tile, BK=32, m97-style K loop.
// Scan: affine-map segment composition; each lane owns 16 states in regs.
// Conv: 8 channels x 16 tokens per thread, sliding register window (weights
// amortized 16x, input rows 4x) — fixes the L1-transaction-bound v1.
// ---------------------------------------------------------------------------

#define DM   1024
#define DI   2048
#define DSTATE 16
#define DTR  64
#define BSZ  4
#define LSEQ 4096
#define NTOK (BSZ * LSEQ)   // 16384
#define NSEG 32             // segments per sequence (parallel scan)
#define SEG  (LSEQ / NSEG)  // 128 steps per segment
#define CT   8              // register-staged steps per sub-chunk
#define TC   16             // tokens per conv thread

typedef _Float16 half8 __attribute__((ext_vector_type(8)));
typedef _Float16 half4v __attribute__((ext_vector_type(4)));
typedef float f32x4 __attribute__((ext_vector_type(4)));

__device__ __forceinline__ void load_lds16(const _Float16* g, _Float16* l) {
    __builtin_amdgcn_global_load_lds(
        (const __attribute__((address_space(1))) void*)g,
        (__attribute__((address_space(3))) void*)l,
        16, 0, 0);
}

// ------------------------------ conversions --------------------------------

__global__ __launch_bounds__(256) void cvt_f32_f16(const float* __restrict__ in,
                                                   _Float16* __restrict__ out,
                                                   long nvec) {
    long i = (long)blockIdx.x * 256 + threadIdx.x;
    if (i >= nvec) return;
    f32x4 v = ((const f32x4*)in)[i];
    half4v o;
    o[0] = (_Float16)v[0]; o[1] = (_Float16)v[1];
    o[2] = (_Float16)v[2]; o[3] = (_Float16)v[3];
    ((half4v*)out)[i] = o;
}

// W_xproj is (96, 2048); pad to (128, 2048) with zeros so the GEMM N-tile is full.
__global__ __launch_bounds__(256) void cvt_pad_wxp(const float* __restrict__ in,
                                                   _Float16* __restrict__ out) {
    int i = blockIdx.x * 256 + threadIdx.x;   // over 128*2048
    int row = i >> 11;
    int col = i & 2047;
    out[i] = (row < 96) ? (_Float16)in[row * 2048 + col] : (_Float16)0.f;
}

// ------------------------------ GEMM (NT) ----------------------------------
// C[m,n] = sum_k A[m,k] * B[n,k].  A: (M,K) fp16 row-major. B: (N,K) fp16
// row-major. 128x128 tile, BK=32, 256 threads (4 waves, 2x2 wave grid, each
// wave 64x64 = 4x4 MFMA 16x16x32 tiles). Epilogue via functor.

struct EpiSplit {          // GEMM1: n<2048 -> xi_raw(f16), else z(f16)
    _Float16* xi; _Float16* z;
    __device__ void store(int m, int n, float v) const {
        if (n < DI) xi[(long)m * DI + n] = (_Float16)v;
        else        z[(long)m * DI + (n - DI)] = (_Float16)v;
    }
};
struct EpiXproj {          // GEMM2: n<64 -> dt_lo(f16); 64..95 -> BC(f32)
    _Float16* dtlo; float* BC;
    __device__ void store(int m, int n, float v) const {
        if (n < DTR)      dtlo[(long)m * DTR + n] = (_Float16)v;
        else if (n < 96)  BC[(long)m * 32 + (n - DTR)] = v;
    }
};
struct EpiDt {             // GEMM3: softplus(v + b_dt[n]) -> dt(f16)
    const float* b_dt; _Float16* dt;
    __device__ void store(int m, int n, float v) const {
        float t = v + b_dt[n];
        float sp = (t > 20.f) ? t : log1pf(__expf(t));
        dt[(long)m * DI + n] = (_Float16)sp;
    }
};
struct EpiOut {            // GEMM4: plain fp32 store
    float* out;
    __device__ void store(int m, int n, float v) const {
        out[(long)m * DM + n] = v;
    }
};

template <class Epi>
__global__ __launch_bounds__(256, 2) void gemm_nt(const _Float16* __restrict__ A,
                                                  const _Float16* __restrict__ B,
                                                  int K, Epi epi) {
    __shared__ __align__(16) _Float16 As[128 * 32];
    __shared__ __align__(16) _Float16 Bs[128 * 32];
    const int tid  = threadIdx.x;
    const int wave = tid >> 6;
    const int ln   = tid & 63;
    const int wm   = wave & 1;      // 2x2 wave grid over the 128x128 tile
    const int wn   = wave >> 1;
    const int lane_m = ln & 15;     // MFMA A/B operand: row/col = lane&15
    const int kg     = ln >> 4;     // k-group: 8 halves each

    const long Abase = (long)blockIdx.y * 128 * K;
    const long Bbase = (long)blockIdx.x * 128 * K;

    f32x4 acc[4][4];
#pragma unroll
    for (int i = 0; i < 4; ++i)
#pragma unroll
        for (int j = 0; j < 4; ++j) acc[i][j] = (f32x4){0.f, 0.f, 0.f, 0.f};

    for (int k0 = 0; k0 < K; k0 += 32) {
        __syncthreads();   // protect LDS from previous iteration's readers
#pragma unroll
        for (int c = 0; c < 2; ++c) {
            int lin = tid + c * 256;           // 0..511
            int row = lin >> 2;                // 128 rows
            int col = (lin & 3) << 3;          // 4 chunks of 8 halves
            load_lds16(A + Abase + (long)row * K + k0 + col,
                       As + (size_t)(wave * 64 + c * 256) * 8);
            load_lds16(B + Bbase + (long)row * K + k0 + col,
                       Bs + (size_t)(wave * 64 + c * 256) * 8);
        }
        asm volatile("s_waitcnt vmcnt(0)" ::: "memory");
        __syncthreads();

        half8 a[4], b[4];
#pragma unroll
        for (int i = 0; i < 4; ++i)
            a[i] = *(const half8*)&As[(wm * 64 + i * 16 + lane_m) * 32 + kg * 8];
#pragma unroll
        for (int j = 0; j < 4; ++j)
            b[j] = *(const half8*)&Bs[(wn * 64 + j * 16 + lane_m) * 32 + kg * 8];
#pragma unroll
        for (int i = 0; i < 4; ++i)
#pragma unroll
            for (int j = 0; j < 4; ++j)
                acc[i][j] = __builtin_amdgcn_mfma_f32_16x16x32_f16(a[i], b[j], acc[i][j], 0, 0, 0);
    }

    // C/D layout: row m = (lane>>4)*4 + reg, col n = lane&15  (verified m89)
#pragma unroll
    for (int i = 0; i < 4; ++i)
#pragma unroll
        for (int j = 0; j < 4; ++j)
#pragma unroll
            for (int r = 0; r < 4; ++r) {
                int m = blockIdx.y * 128 + wm * 64 + i * 16 + kg * 4 + r;
                int n = blockIdx.x * 128 + wn * 64 + j * 16 + lane_m;
                epi.store(m, n, acc[i][j][r]);
            }
}

// --------------------------- depthwise conv + SiLU -------------------------
// Each thread: 8 channels x TC consecutive tokens. conv_w/bias in registers
// (amortized over TC tokens); 4-deep sliding window of input rows (each row
// loaded once). All global accesses stay 1KB/wave coalesced.

__global__ __launch_bounds__(256) void conv_silu(const _Float16* __restrict__ xi_raw,
                                                 const float* __restrict__ conv_w,
                                                 const float* __restrict__ conv_b,
                                                 _Float16* __restrict__ xi_out) {
    const int chunk = blockIdx.x;              // NTOK/TC chunks
    const int b  = chunk / (LSEQ / TC);
    const int lc = (chunk % (LSEQ / TC)) * TC;
    const int d0 = threadIdx.x * 8;

    float wr[4][8], bias[8];
#pragma unroll
    for (int e = 0; e < 8; ++e) {
        f32x4 cw = *(const f32x4*)&conv_w[(d0 + e) * 4];
        wr[0][e] = cw[0]; wr[1][e] = cw[1]; wr[2][e] = cw[2]; wr[3][e] = cw[3];
        bias[e] = conv_b[d0 + e];
    }

    const _Float16* base = xi_raw + (long)b * LSEQ * DI + d0;
    _Float16*       obase = xi_out + (long)b * LSEQ * DI + d0;

    half8 win[4];                              // rows l-3 .. l
#pragma unroll
    for (int j = 0; j < 4; ++j) {
        int ls = lc - 3 + j;
        if (ls >= 0) win[j] = *(const half8*)&base[(long)ls * DI];
        else {
            half8 zz; 
#pragma unroll
            for (int e = 0; e < 8; ++e) zz[e] = (_Float16)0.f;
            win[j] = zz;
        }
    }

    for (int t = 0; t < TC; ++t) {
        int l = lc + t;
        half8 o;
#pragma unroll
        for (int e = 0; e < 8; ++e) {
            float s = bias[e];
#pragma unroll
            for (int j = 0; j < 4; ++j)
                s = fmaf((float)win[j][e], wr[j][e], s);
            o[e] = (_Float16)(s / (1.f + __expf(-s)));
        }
        *(half8*)&obase[(long)l * DI] = o;
        win[0] = win[1]; win[1] = win[2]; win[2] = win[3];
        if (t + 1 < TC) win[3] = *(const half8*)&base[(long)(l + 1) * DI];
    }
}

// ------------------------- parallel selective scan -------------------------
// h_t = dA_t * h_{t-1} + (dt*x)_t * B_t  is an affine map in h; segments
// compose: out = P*in + H with P = prod(dA), H = local scan from h=0.
// part1: per (b, d-lane, seg) compute P[16], H[16].           (no LDS)
// part2: per (b, d, n) serial scan over NSEG segments -> hin (in-place on P).
// part3: replay each segment from hin, produce gated y.       (no LDS)

__global__ __launch_bounds__(256) void scan_part1(const _Float16* __restrict__ dt,
                                                  const _Float16* __restrict__ xi,
                                                  const float* __restrict__ BC,
                                                  const float* __restrict__ A_log,
                                                  float* __restrict__ Pout,
                                                  float* __restrict__ Hout) {
    const int d   = blockIdx.x * 256 + threadIdx.x;
    const int seg = blockIdx.y;
    const int b   = blockIdx.z;

    float A[16], P[16], h[16];
#pragma unroll
    for (int n = 0; n < 16; ++n) {
        A[n] = -__expf(A_log[d * DSTATE + n]);
        P[n] = 1.f;
        h[n] = 0.f;
    }
    const long t0 = (long)b * LSEQ + (long)seg * SEG;
    const _Float16* dp = dt + t0 * DI + d;
    const _Float16* xp = xi + t0 * DI + d;
    const float*    bp = BC + t0 * 32;

    for (int cc = 0; cc < SEG / CT; ++cc) {
        _Float16 ldt[CT], lx[CT];
#pragma unroll
        for (int j = 0; j < CT; ++j) {           // independent coalesced loads
            long o = (long)(cc * CT + j) * DI;
            ldt[j] = dp[o];
            lx[j]  = xp[o];
        }
#pragma unroll
        for (int j = 0; j < CT; ++j) {
            const float* row = bp + (cc * CT + j) * 32;
            f32x4 Bq[4];
#pragma unroll
            for (int q = 0; q < 4; ++q) Bq[q] = *(const f32x4*)(row + q * 4);
            float dtf = (float)ldt[j];
            float u   = dtf * (float)lx[j];
#pragma unroll
            for (int n = 0; n < 16; ++n) {
                float dA = __expf(dtf * A[n]);
                P[n] *= dA;
                h[n] = fmaf(dA, h[n], u * Bq[n >> 2][n & 3]);
            }
        }
    }
    float* po = Pout + (((long)b * NSEG + seg) * DI + d) * 16;
    float* ho = Hout + (((long)b * NSEG + seg) * DI + d) * 16;
#pragma unroll
    for (int q = 0; q < 4; ++q) {
        *(f32x4*)(po + q * 4) = (f32x4){P[q*4], P[q*4+1], P[q*4+2], P[q*4+3]};
        *(f32x4*)(ho + q * 4) = (f32x4){h[q*4], h[q*4+1], h[q*4+2], h[q*4+3]};
    }
}

// NOTE: hin aliases P (in-place). Per-thread: P[idx]/H[idx] are loaded into
// registers BEFORE hin[idx] is stored; each idx is touched by exactly one
// thread. No __restrict__ here so the compiler respects the aliasing.
__global__ __launch_bounds__(256) void scan_part2(const float* P,
                                                  const float* H,
                                                  float* hin) {
    long t = (long)blockIdx.x * 256 + threadIdx.x;   // BSZ*DI*16 = 131072
    int  n = (int)(t & 15);
    long d = (t >> 4) & (DI - 1);
    int  b = (int)(t >> 15);
    float h = 0.f;
    for (int s = 0; s < NSEG; ++s) {
        long idx = (((long)b * NSEG + s) * DI + d) * 16 + n;
        float p  = P[idx];
        float hh = H[idx];
        hin[idx] = h;                       // state entering segment s
        h = fmaf(p, h, hh);
    }
}

__global__ __launch_bounds__(256) void scan_part3(const _Float16* __restrict__ dt,
                                                  const _Float16* __restrict__ xi,
                                                  const _Float16* z,      // aliases y
                                                  const float* __restrict__ BC,
                                                  const float* __restrict__ A_log,
                                                  const float* __restrict__ D_param,
                                                  const float* __restrict__ hin,
                                                  _Float16* y) {
    const int d   = blockIdx.x * 256 + threadIdx.x;
    const int seg = blockIdx.y;
    const int b   = blockIdx.z;

    float A[16], h[16];
    const float* hi = hin + (((long)b * NSEG + seg) * DI + d) * 16;
#pragma unroll
    for (int n = 0; n < 16; ++n) {
        A[n] = -__expf(A_log[d * DSTATE + n]);
        h[n] = hi[n];
    }
    const float Dd = D_param[d];
    const long t0 = (long)b * LSEQ + (long)seg * SEG;
    const _Float16* dp = dt + t0 * DI + d;
    const _Float16* xp = xi + t0 * DI + d;
    const _Float16* zp = z  + t0 * DI + d;
    _Float16*       yp = y  + t0 * DI + d;
    const float*    bp = BC + t0 * 32;

    for (int cc = 0; cc < SEG / CT; ++cc) {
        _Float16 ldt[CT], lx[CT], lz[CT];
#pragma unroll
        for (int j = 0; j < CT; ++j) {
            long o = (long)(cc * CT + j) * DI;
            ldt[j] = dp[o];
            lx[j]  = xp[o];
            lz[j]  = zp[o];
        }
#pragma unroll
        for (int j = 0; j < CT; ++j) {
            const float* row = bp + (cc * CT + j) * 32;
            f32x4 Bq[4], Cq[4];
#pragma unroll
            for (int q = 0; q < 4; ++q) {
                Bq[q] = *(const f32x4*)(row + q * 4);
                Cq[q] = *(const f32x4*)(row + 16 + q * 4);
            }
            float dtf = (float)ldt[j];
            float xf  = (float)lx[j];
            float u   = dtf * xf;
            float a0 = 0.f, a1 = 0.f, a2 = 0.f, a3 = 0.f;
#pragma unroll
            for (int n = 0; n < 16; ++n) {
                float dA = __expf(dtf * A[n]);
                h[n] = fmaf(dA, h[n], u * Bq[n >> 2][n & 3]);
                float c = Cq[n >> 2][n & 3];
                if ((n & 3) == 0) a0 = fmaf(h[n], c, a0);
                else if ((n & 3) == 1) a1 = fmaf(h[n], c, a1);
                else if ((n & 3) == 2) a2 = fmaf(h[n], c, a2);
                else a3 = fmaf(h[n], c, a3);
            }
            float ys = (a0 + a1) + (a2 + a3);
            float zf = (float)lz[j];
            float g  = zf / (1.f + __expf(-zf));
            yp[(long)(cc * CT + j) * DI] = (_Float16)((ys + xf * Dd) * g);
        }
    }
}

// ------------------------------ launch -------------------------------------

extern "C" void kernel_launch(void* const* d_in, const int* in_sizes, int n_in,
                              void* d_out, int out_size, void* d_ws, size_t ws_size,
                              hipStream_t stream) {
    const float* x       = (const float*)d_in[0];
    const float* W_in    = (const float*)d_in[1];
    const float* conv_w  = (const float*)d_in[2];
    const float* conv_b  = (const float*)d_in[3];
    const float* W_xproj = (const float*)d_in[4];
    const float* W_dt    = (const float*)d_in[5];
    const float* b_dt    = (const float*)d_in[6];
    const float* A_log   = (const float*)d_in[7];
    const float* D_param = (const float*)d_in[8];
    const float* W_out   = (const float*)d_in[9];
    float* out = (float*)d_out;

    char* w = (char*)d_ws;
    size_t off = 0;
    auto alloc = [&](size_t bytes) {
        void* p = w + off;
        off += (bytes + 255) & ~(size_t)255;
        return p;
    };
    // x_h and Win_h are adjacent => contiguous 40 MB region, dead after GEMM1;
    // it hosts Pseg (16.8 MB) + Hseg (16.8 MB) during the scan.
    _Float16* x_h    = (_Float16*)alloc((size_t)NTOK * DM * 2);     // 32 MB
    _Float16* Win_h  = (_Float16*)alloc((size_t)2 * DI * DM * 2);   // 8 MB
    _Float16* Wout_h = (_Float16*)alloc((size_t)DM * DI * 2);       // 4 MB
    _Float16* Wxp_h  = (_Float16*)alloc((size_t)128 * DI * 2);      // 0.5 MB (padded 96->128)
    _Float16* Wdt_h  = (_Float16*)alloc((size_t)DI * DTR * 2);      // 0.25 MB
    _Float16* xi_raw = (_Float16*)alloc((size_t)NTOK * DI * 2);     // 64 MB (reused as dt)
    _Float16* z_h    = (_Float16*)alloc((size_t)NTOK * DI * 2);     // 64 MB (reused as y)
    _Float16* xi_h   = (_Float16*)alloc((size_t)NTOK * DI * 2);     // 64 MB
    _Float16* dtlo_h = (_Float16*)alloc((size_t)NTOK * DTR * 2);    // 2 MB
    float*    BC     = (float*)alloc((size_t)NTOK * 32 * 4);        // 2 MB
    _Float16* dt_h = xi_raw;   // xi_raw dead after conv (conv runs before GEMM3)
    _Float16* y_h  = z_h;      // scan part3: z read staged before y store, same thread
    const size_t seg_bytes = (size_t)BSZ * NSEG * DI * 16 * 4;      // 16.8 MB
    float* Pseg = (float*)x_h;                                      // aliases x_h
    float* Hseg = (float*)((char*)x_h + ((seg_bytes + 255) & ~(size_t)255)); // spills into Win_h
    float* hin  = Pseg;        // part2 overwrites P in place (read-before-write)

    // conversions
    cvt_f32_f16<<<(NTOK * DM / 4) / 256, 256, 0, stream>>>(x, x_h, NTOK * DM / 4);
    cvt_f32_f16<<<(2 * DI * DM / 4) / 256, 256, 0, stream>>>(W_in, Win_h, 2 * DI * DM / 4);
    cvt_f32_f16<<<(DM * DI / 4) / 256, 256, 0, stream>>>(W_out, Wout_h, DM * DI / 4);
    cvt_f32_f16<<<(DI * DTR / 4) / 256, 256, 0, stream>>>(W_dt, Wdt_h, DI * DTR / 4);
    cvt_pad_wxp<<<(128 * DI) / 256, 256, 0, stream>>>(W_xproj, Wxp_h);

    // GEMM1: (16384,1024) @ (4096,1024)^T -> split xi / z
    gemm_nt<EpiSplit><<<dim3(2 * DI / 128, NTOK / 128), 256, 0, stream>>>(
        x_h, Win_h, DM, EpiSplit{xi_raw, z_h});

    // causal depthwise conv (k=4) + bias + SiLU
    conv_silu<<<NTOK / TC, 256, 0, stream>>>(xi_raw, conv_w, conv_b, xi_h);

    // GEMM2: (16384,2048) @ (96,2048)^T -> dt_lo (f16) + B/C (f32)
    gemm_nt<EpiXproj><<<dim3(1, NTOK / 128), 256, 0, stream>>>(
        xi_h, Wxp_h, DI, EpiXproj{dtlo_h, BC});

    // GEMM3: (16384,64) @ (2048,64)^T + b_dt -> softplus -> dt (f16)
    gemm_nt<EpiDt><<<dim3(DI / 128, NTOK / 128), 256, 0, stream>>>(
        dtlo_h, Wdt_h, DTR, EpiDt{b_dt, dt_h});

    // parallel selective scan (P/H/hin live in the dead x_h/Win_h region)
    scan_part1<<<dim3(DI / 256, NSEG, BSZ), 256, 0, stream>>>(
        dt_h, xi_h, BC, A_log, Pseg, Hseg);
    scan_part2<<<(BSZ * DI * 16) / 256, 256, 0, stream>>>(Pseg, Hseg, hin);
    scan_part3<<<dim3(DI / 256, NSEG, BSZ), 256, 0, stream>>>(
        dt_h, xi_h, z_h, BC, A_log, D_param, hin, y_h);

    // GEMM4: (16384,2048) @ (1024,2048)^T -> out (f32)
    gemm_nt<EpiOut><<<dim3(DM / 128, NTOK / 128), 256, 0, stream>>>(
        y_h, Wout_h, DI, EpiOut{out});
}

// Round 6
// 731.099 us; speedup vs baseline: 4.4622x; 1.2054x over previous
//
#include <hip/hip_runtime.h>

// ---------------------------------------------------------------------------
// SelectiveSSM (Mamba block) forward on MI355X / gfx950.
// Pipeline: cvt(fp32->fp16) -> GEMM1 (x@W_in^T, split xi/z) -> causal depthwise
// conv+SiLU -> GEMM2 (xi@W_xproj^T, split dt_lo/B/C) -> GEMM3 (dt_lo@W_dt^T +
// b_dt, fast softplus) -> 3-phase parallel selective scan -> GEMM4.
// GEMMs: fp16 MFMA 16x16x32, TMx128 tile (TM=128; TM=64 for the skinny GEMM2
// to double grid parallelism), BK=32, m97-style K loop.
// Scan: affine-map segment composition; each lane owns 16 states in regs.
// Conv: 8 channels x 16 tokens per thread, sliding register window.
// ---------------------------------------------------------------------------

#define DM   1024
#define DI   2048
#define DSTATE 16
#define DTR  64
#define BSZ  4
#define LSEQ 4096
#define NTOK (BSZ * LSEQ)   // 16384
#define NSEG 32             // segments per sequence (parallel scan)
#define SEG  (LSEQ / NSEG)  // 128 steps per segment
#define CT   8              // register-staged steps per sub-chunk
#define TC   16             // tokens per conv thread

typedef _Float16 half8 __attribute__((ext_vector_type(8)));
typedef _Float16 half4v __attribute__((ext_vector_type(4)));
typedef float f32x4 __attribute__((ext_vector_type(4)));

__device__ __forceinline__ void load_lds16(const _Float16* g, _Float16* l) {
    __builtin_amdgcn_global_load_lds(
        (const __attribute__((address_space(1))) void*)g,
        (__attribute__((address_space(3))) void*)l,
        16, 0, 0);
}

// ------------------------------ conversions --------------------------------

__global__ __launch_bounds__(256) void cvt_f32_f16(const float* __restrict__ in,
                                                   _Float16* __restrict__ out,
                                                   long nvec) {
    long i = (long)blockIdx.x * 256 + threadIdx.x;
    if (i >= nvec) return;
    f32x4 v = ((const f32x4*)in)[i];
    half4v o;
    o[0] = (_Float16)v[0]; o[1] = (_Float16)v[1];
    o[2] = (_Float16)v[2]; o[3] = (_Float16)v[3];
    ((half4v*)out)[i] = o;
}

// W_xproj is (96, 2048); pad to (128, 2048) with zeros so the GEMM N-tile is full.
__global__ __launch_bounds__(256) void cvt_pad_wxp(const float* __restrict__ in,
                                                   _Float16* __restrict__ out) {
    int i = blockIdx.x * 256 + threadIdx.x;   // over 128*2048
    int row = i >> 11;
    int col = i & 2047;
    out[i] = (row < 96) ? (_Float16)in[row * 2048 + col] : (_Float16)0.f;
}

// ------------------------------ GEMM (NT) ----------------------------------
// C[m,n] = sum_k A[m,k] * B[n,k].  A: (M,K) fp16 row-major. B: (N,K) fp16
// row-major. TMx128 tile, BK=32, 256 threads (4 waves, 2x2 wave grid; each
// wave (TM/2)x64 = (TM/32)x4 MFMA 16x16x32 tiles). Epilogue via functor.

struct EpiSplit {          // GEMM1: n<2048 -> xi_raw(f16), else z(f16)
    _Float16* xi; _Float16* z;
    __device__ void store(int m, int n, float v) const {
        if (n < DI) xi[(long)m * DI + n] = (_Float16)v;
        else        z[(long)m * DI + (n - DI)] = (_Float16)v;
    }
};
struct EpiXproj {          // GEMM2: n<64 -> dt_lo(f16); 64..95 -> BC(f32)
    _Float16* dtlo; float* BC;
    __device__ void store(int m, int n, float v) const {
        if (n < DTR)      dtlo[(long)m * DTR + n] = (_Float16)v;
        else if (n < 96)  BC[(long)m * 32 + (n - DTR)] = v;
    }
};
struct EpiDt {             // GEMM3: fast softplus(v + b_dt[n]) -> dt(f16)
    const float* b_dt; _Float16* dt;
    __device__ void store(int m, int n, float v) const {
        float t = v + b_dt[n];
        // softplus(t) = max(t,0) + log(1+exp(-|t|)); hw v_exp/v_log, ~8 VALU
        float sp = fmaxf(t, 0.f) + __logf(1.f + __expf(-fabsf(t)));
        dt[(long)m * DI + n] = (_Float16)sp;
    }
};
struct EpiOut {            // GEMM4: plain fp32 store
    float* out;
    __device__ void store(int m, int n, float v) const {
        out[(long)m * DM + n] = v;
    }
};

template <int TM, class Epi>
__global__ __launch_bounds__(256, 2) void gemm_nt(const _Float16* __restrict__ A,
                                                  const _Float16* __restrict__ B,
                                                  int K, Epi epi) {
    constexpr int MI = TM / 32;            // MFMA m-tiles per wave
    __shared__ __align__(16) _Float16 As[TM * 32];
    __shared__ __align__(16) _Float16 Bs[128 * 32];
    const int tid  = threadIdx.x;
    const int wave = tid >> 6;
    const int ln   = tid & 63;
    const int wm   = wave & 1;      // 2x2 wave grid over the TMx128 tile
    const int wn   = wave >> 1;
    const int lane_m = ln & 15;     // MFMA A/B operand: row/col = lane&15
    const int kg     = ln >> 4;     // k-group: 8 halves each

    const long Abase = (long)blockIdx.y * TM * K;
    const long Bbase = (long)blockIdx.x * 128 * K;

    f32x4 acc[MI][4];
#pragma unroll
    for (int i = 0; i < MI; ++i)
#pragma unroll
        for (int j = 0; j < 4; ++j) acc[i][j] = (f32x4){0.f, 0.f, 0.f, 0.f};

    for (int k0 = 0; k0 < K; k0 += 32) {
        __syncthreads();   // protect LDS from previous iteration's readers
#pragma unroll
        for (int c = 0; c < TM / 64; ++c) {    // A tile: TM rows x 32 cols
            int lin = tid + c * 256;
            int row = lin >> 2;
            int col = (lin & 3) << 3;
            load_lds16(A + Abase + (long)row * K + k0 + col,
                       As + (size_t)(wave * 64 + c * 256) * 8);
        }
#pragma unroll
        for (int c = 0; c < 2; ++c) {          // B tile: 128 rows x 32 cols
            int lin = tid + c * 256;
            int row = lin >> 2;
            int col = (lin & 3) << 3;
            load_lds16(B + Bbase + (long)row * K + k0 + col,
                       Bs + (size_t)(wave * 64 + c * 256) * 8);
        }
        asm volatile("s_waitcnt vmcnt(0)" ::: "memory");
        __syncthreads();

        half8 a[MI], b[4];
#pragma unroll
        for (int i = 0; i < MI; ++i)
            a[i] = *(const half8*)&As[(wm * (TM / 2) + i * 16 + lane_m) * 32 + kg * 8];
#pragma unroll
        for (int j = 0; j < 4; ++j)
            b[j] = *(const half8*)&Bs[(wn * 64 + j * 16 + lane_m) * 32 + kg * 8];
#pragma unroll
        for (int i = 0; i < MI; ++i)
#pragma unroll
            for (int j = 0; j < 4; ++j)
                acc[i][j] = __builtin_amdgcn_mfma_f32_16x16x32_f16(a[i], b[j], acc[i][j], 0, 0, 0);
    }

    // C/D layout: row m = (lane>>4)*4 + reg, col n = lane&15  (verified m89)
#pragma unroll
    for (int i = 0; i < MI; ++i)
#pragma unroll
        for (int j = 0; j < 4; ++j)
#pragma unroll
            for (int r = 0; r < 4; ++r) {
                int m = blockIdx.y * TM + wm * (TM / 2) + i * 16 + kg * 4 + r;
                int n = blockIdx.x * 128 + wn * 64 + j * 16 + lane_m;
                epi.store(m, n, acc[i][j][r]);
            }
}

// --------------------------- depthwise conv + SiLU -------------------------
// Each thread: 8 channels x TC consecutive tokens. conv_w/bias in registers
// (amortized over TC tokens); 4-deep sliding window of input rows (each row
// loaded once). All global accesses stay 1KB/wave coalesced.

__global__ __launch_bounds__(256) void conv_silu(const _Float16* __restrict__ xi_raw,
                                                 const float* __restrict__ conv_w,
                                                 const float* __restrict__ conv_b,
                                                 _Float16* __restrict__ xi_out) {
    const int chunk = blockIdx.x;              // NTOK/TC chunks
    const int b  = chunk / (LSEQ / TC);
    const int lc = (chunk % (LSEQ / TC)) * TC;
    const int d0 = threadIdx.x * 8;

    float wr[4][8], bias[8];
#pragma unroll
    for (int e = 0; e < 8; ++e) {
        f32x4 cw = *(const f32x4*)&conv_w[(d0 + e) * 4];
        wr[0][e] = cw[0]; wr[1][e] = cw[1]; wr[2][e] = cw[2]; wr[3][e] = cw[3];
        bias[e] = conv_b[d0 + e];
    }

    const _Float16* base = xi_raw + (long)b * LSEQ * DI + d0;
    _Float16*       obase = xi_out + (long)b * LSEQ * DI + d0;

    half8 win[4];                              // rows l-3 .. l
#pragma unroll
    for (int j = 0; j < 4; ++j) {
        int ls = lc - 3 + j;
        if (ls >= 0) win[j] = *(const half8*)&base[(long)ls * DI];
        else {
            half8 zz;
#pragma unroll
            for (int e = 0; e < 8; ++e) zz[e] = (_Float16)0.f;
            win[j] = zz;
        }
    }

    for (int t = 0; t < TC; ++t) {
        int l = lc + t;
        half8 o;
#pragma unroll
        for (int e = 0; e < 8; ++e) {
            float s = bias[e];
#pragma unroll
            for (int j = 0; j < 4; ++j)
                s = fmaf((float)win[j][e], wr[j][e], s);
            o[e] = (_Float16)(s / (1.f + __expf(-s)));
        }
        *(half8*)&obase[(long)l * DI] = o;
        win[0] = win[1]; win[1] = win[2]; win[2] = win[3];
        if (t + 1 < TC) win[3] = *(const half8*)&base[(long)(l + 1) * DI];
    }
}

// ------------------------- parallel selective scan -------------------------
// h_t = dA_t * h_{t-1} + (dt*x)_t * B_t  is an affine map in h; segments
// compose: out = P*in + H with P = prod(dA), H = local scan from h=0.
// part1: per (b, d-lane, seg) compute P[16], H[16].           (no LDS)
// part2: per (b, d, n) serial scan over NSEG segments -> hin (in-place on P).
// part3: replay each segment from hin, produce gated y.       (no LDS)

__global__ __launch_bounds__(256) void scan_part1(const _Float16* __restrict__ dt,
                                                  const _Float16* __restrict__ xi,
                                                  const float* __restrict__ BC,
                                                  const float* __restrict__ A_log,
                                                  float* __restrict__ Pout,
                                                  float* __restrict__ Hout) {
    const int d   = blockIdx.x * 256 + threadIdx.x;
    const int seg = blockIdx.y;
    const int b   = blockIdx.z;

    float A[16], P[16], h[16];
#pragma unroll
    for (int n = 0; n < 16; ++n) {
        A[n] = -__expf(A_log[d * DSTATE + n]);
        P[n] = 1.f;
        h[n] = 0.f;
    }
    const long t0 = (long)b * LSEQ + (long)seg * SEG;
    const _Float16* dp = dt + t0 * DI + d;
    const _Float16* xp = xi + t0 * DI + d;
    const float*    bp = BC + t0 * 32;

    for (int cc = 0; cc < SEG / CT; ++cc) {
        _Float16 ldt[CT], lx[CT];
#pragma unroll
        for (int j = 0; j < CT; ++j) {           // independent coalesced loads
            long o = (long)(cc * CT + j) * DI;
            ldt[j] = dp[o];
            lx[j]  = xp[o];
        }
#pragma unroll
        for (int j = 0; j < CT; ++j) {
            const float* row = bp + (cc * CT + j) * 32;
            f32x4 Bq[4];
#pragma unroll
            for (int q = 0; q < 4; ++q) Bq[q] = *(const f32x4*)(row + q * 4);
            float dtf = (float)ldt[j];
            float u   = dtf * (float)lx[j];
#pragma unroll
            for (int n = 0; n < 16; ++n) {
                float dA = __expf(dtf * A[n]);
                P[n] *= dA;
                h[n] = fmaf(dA, h[n], u * Bq[n >> 2][n & 3]);
            }
        }
    }
    float* po = Pout + (((long)b * NSEG + seg) * DI + d) * 16;
    float* ho = Hout + (((long)b * NSEG + seg) * DI + d) * 16;
#pragma unroll
    for (int q = 0; q < 4; ++q) {
        *(f32x4*)(po + q * 4) = (f32x4){P[q*4], P[q*4+1], P[q*4+2], P[q*4+3]};
        *(f32x4*)(ho + q * 4) = (f32x4){h[q*4], h[q*4+1], h[q*4+2], h[q*4+3]};
    }
}

// NOTE: hin aliases P (in-place). Per-thread: P[idx]/H[idx] are loaded into
// registers BEFORE hin[idx] is stored; each idx is touched by exactly one
// thread. No __restrict__ here so the compiler respects the aliasing.
__global__ __launch_bounds__(256) void scan_part2(const float* P,
                                                  const float* H,
                                                  float* hin) {
    long t = (long)blockIdx.x * 256 + threadIdx.x;   // BSZ*DI*16 = 131072
    int  n = (int)(t & 15);
    long d = (t >> 4) & (DI - 1);
    int  b = (int)(t >> 15);
    float h = 0.f;
    for (int s = 0; s < NSEG; ++s) {
        long idx = (((long)b * NSEG + s) * DI + d) * 16 + n;
        float p  = P[idx];
        float hh = H[idx];
        hin[idx] = h;                       // state entering segment s
        h = fmaf(p, h, hh);
    }
}

__global__ __launch_bounds__(256) void scan_part3(const _Float16* __restrict__ dt,
                                                  const _Float16* __restrict__ xi,
                                                  const _Float16* z,      // aliases y
                                                  const float* __restrict__ BC,
                                                  const float* __restrict__ A_log,
                                                  const float* __restrict__ D_param,
                                                  const float* __restrict__ hin,
                                                  _Float16* y) {
    const int d   = blockIdx.x * 256 + threadIdx.x;
    const int seg = blockIdx.y;
    const int b   = blockIdx.z;

    float A[16], h[16];
    const float* hi = hin + (((long)b * NSEG + seg) * DI + d) * 16;
#pragma unroll
    for (int n = 0; n < 16; ++n) {
        A[n] = -__expf(A_log[d * DSTATE + n]);
        h[n] = hi[n];
    }
    const float Dd = D_param[d];
    const long t0 = (long)b * LSEQ + (long)seg * SEG;
    const _Float16* dp = dt + t0 * DI + d;
    const _Float16* xp = xi + t0 * DI + d;
    const _Float16* zp = z  + t0 * DI + d;
    _Float16*       yp = y  + t0 * DI + d;
    const float*    bp = BC + t0 * 32;

    for (int cc = 0; cc < SEG / CT; ++cc) {
        _Float16 ldt[CT], lx[CT], lz[CT];
#pragma unroll
        for (int j = 0; j < CT; ++j) {
            long o = (long)(cc * CT + j) * DI;
            ldt[j] = dp[o];
            lx[j]  = xp[o];
            lz[j]  = zp[o];
        }
#pragma unroll
        for (int j = 0; j < CT; ++j) {
            const float* row = bp + (cc * CT + j) * 32;
            f32x4 Bq[4], Cq[4];
#pragma unroll
            for (int q = 0; q < 4; ++q) {
                Bq[q] = *(const f32x4*)(row + q * 4);
                Cq[q] = *(const f32x4*)(row + 16 + q * 4);
            }
            float dtf = (float)ldt[j];
            float xf  = (float)lx[j];
            float u   = dtf * xf;
            float a0 = 0.f, a1 = 0.f, a2 = 0.f, a3 = 0.f;
#pragma unroll
            for (int n = 0; n < 16; ++n) {
                float dA = __expf(dtf * A[n]);
                h[n] = fmaf(dA, h[n], u * Bq[n >> 2][n & 3]);
                float c = Cq[n >> 2][n & 3];
                if ((n & 3) == 0) a0 = fmaf(h[n], c, a0);
                else if ((n & 3) == 1) a1 = fmaf(h[n], c, a1);
                else if ((n & 3) == 2) a2 = fmaf(h[n], c, a2);
                else a3 = fmaf(h[n], c, a3);
            }
            float ys = (a0 + a1) + (a2 + a3);
            float zf = (float)lz[j];
            float g  = zf / (1.f + __expf(-zf));
            yp[(long)(cc * CT + j) * DI] = (_Float16)((ys + xf * Dd) * g);
        }
    }
}

// ------------------------------ launch -------------------------------------

extern "C" void kernel_launch(void* const* d_in, const int* in_sizes, int n_in,
                              void* d_out, int out_size, void* d_ws, size_t ws_size,
                              hipStream_t stream) {
    const float* x       = (const float*)d_in[0];
    const float* W_in    = (const float*)d_in[1];
    const float* conv_w  = (const float*)d_in[2];
    const float* conv_b  = (const float*)d_in[3];
    const float* W_xproj = (const float*)d_in[4];
    const float* W_dt    = (const float*)d_in[5];
    const float* b_dt    = (const float*)d_in[6];
    const float* A_log   = (const float*)d_in[7];
    const float* D_param = (const float*)d_in[8];
    const float* W_out   = (const float*)d_in[9];
    float* out = (float*)d_out;

    char* w = (char*)d_ws;
    size_t off = 0;
    auto alloc = [&](size_t bytes) {
        void* p = w + off;
        off += (bytes + 255) & ~(size_t)255;
        return p;
    };
    // x_h and Win_h are adjacent => contiguous 40 MB region, dead after GEMM1;
    // it hosts Pseg (16.8 MB) + Hseg (16.8 MB) during the scan.
    _Float16* x_h    = (_Float16*)alloc((size_t)NTOK * DM * 2);     // 32 MB
    _Float16* Win_h  = (_Float16*)alloc((size_t)2 * DI * DM * 2);   // 8 MB
    _Float16* Wout_h = (_Float16*)alloc((size_t)DM * DI * 2);       // 4 MB
    _Float16* Wxp_h  = (_Float16*)alloc((size_t)128 * DI * 2);      // 0.5 MB (padded 96->128)
    _Float16* Wdt_h  = (_Float16*)alloc((size_t)DI * DTR * 2);      // 0.25 MB
    _Float16* xi_raw = (_Float16*)alloc((size_t)NTOK * DI * 2);     // 64 MB (reused as dt)
    _Float16* z_h    = (_Float16*)alloc((size_t)NTOK * DI * 2);     // 64 MB (reused as y)
    _Float16* xi_h   = (_Float16*)alloc((size_t)NTOK * DI * 2);     // 64 MB
    _Float16* dtlo_h = (_Float16*)alloc((size_t)NTOK * DTR * 2);    // 2 MB
    float*    BC     = (float*)alloc((size_t)NTOK * 32 * 4);        // 2 MB
    _Float16* dt_h = xi_raw;   // xi_raw dead after conv (conv runs before GEMM3)
    _Float16* y_h  = z_h;      // scan part3: z read staged before y store, same thread
    const size_t seg_bytes = (size_t)BSZ * NSEG * DI * 16 * 4;      // 16.8 MB
    float* Pseg = (float*)x_h;                                      // aliases x_h
    float* Hseg = (float*)((char*)x_h + ((seg_bytes + 255) & ~(size_t)255)); // spills into Win_h
    float* hin  = Pseg;        // part2 overwrites P in place (read-before-write)

    // conversions
    cvt_f32_f16<<<(NTOK * DM / 4) / 256, 256, 0, stream>>>(x, x_h, NTOK * DM / 4);
    cvt_f32_f16<<<(2 * DI * DM / 4) / 256, 256, 0, stream>>>(W_in, Win_h, 2 * DI * DM / 4);
    cvt_f32_f16<<<(DM * DI / 4) / 256, 256, 0, stream>>>(W_out, Wout_h, DM * DI / 4);
    cvt_f32_f16<<<(DI * DTR / 4) / 256, 256, 0, stream>>>(W_dt, Wdt_h, DI * DTR / 4);
    cvt_pad_wxp<<<(128 * DI) / 256, 256, 0, stream>>>(W_xproj, Wxp_h);

    // GEMM1: (16384,1024) @ (4096,1024)^T -> split xi / z
    gemm_nt<128, EpiSplit><<<dim3(2 * DI / 128, NTOK / 128), 256, 0, stream>>>(
        x_h, Win_h, DM, EpiSplit{xi_raw, z_h});

    // causal depthwise conv (k=4) + bias + SiLU
    conv_silu<<<NTOK / TC, 256, 0, stream>>>(xi_raw, conv_w, conv_b, xi_h);

    // GEMM2: (16384,2048) @ (96,2048)^T -> dt_lo (f16) + B/C (f32); TM=64
    gemm_nt<64, EpiXproj><<<dim3(1, NTOK / 64), 256, 0, stream>>>(
        xi_h, Wxp_h, DI, EpiXproj{dtlo_h, BC});

    // GEMM3: (16384,64) @ (2048,64)^T + b_dt -> fast softplus -> dt (f16)
    gemm_nt<128, EpiDt><<<dim3(DI / 128, NTOK / 128), 256, 0, stream>>>(
        dtlo_h, Wdt_h, DTR, EpiDt{b_dt, dt_h});

    // parallel selective scan (P/H/hin live in the dead x_h/Win_h region)
    scan_part1<<<dim3(DI / 256, NSEG, BSZ), 256, 0, stream>>>(
        dt_h, xi_h, BC, A_log, Pseg, Hseg);
    scan_part2<<<(BSZ * DI * 16) / 256, 256, 0, stream>>>(Pseg, Hseg, hin);
    scan_part3<<<dim3(DI / 256, NSEG, BSZ), 256, 0, stream>>>(
        dt_h, xi_h, z_h, BC, A_log, D_param, hin, y_h);

    // GEMM4: (16384,2048) @ (1024,2048)^T -> out (f32)
    gemm_nt<128, EpiOut><<<dim3(DM / 128, NTOK / 128), 256, 0, stream>>>(
        y_h, Wout_h, DI, EpiOut{out});
}